// Round 3
// baseline (4094.985 us; speedup 1.0000x reference)
//
#include <hip/hip_runtime.h>
#include <hip/hip_bf16.h>
#include <float.h>
#include <math.h>

#define DEVFN __device__ __forceinline__

namespace {
constexpr int Bq = 4, Nq = 8192, Cq = 32, Kq = 16;
constexpr int PTS = Bq * Nq;          // 32768 points
constexpr int CH = 8;                  // knn candidate chunks
constexpr int CAND = Nq / CH;          // 1024 candidates per chunk
constexpr double ROWS = 524288.0;      // PTS * Kq

// stat/bnp region bases (each region: [sum|mean x128][sumsq|scale x128])
constexpr int DS_Y = 0, DS_Z = 256, DS_G = 512, DS_H1 = 768, DS_H2 = 1024;

// workspace byte offsets
constexpr size_t OFF_A   = 0;                         // knn_d (16MB) -> reused as g_raw
constexpr size_t OFF_B   = (size_t)16 << 20;          // knn_j (16MB) -> reused as agg
constexpr size_t OFF_IDX = (size_t)32 << 20;          // idx (2MB)
constexpr size_t OFF_DST = (size_t)34 << 20;          // dstat (1280 doubles)
constexpr size_t OFF_BNP = ((size_t)34 << 20) + 16384;  // bnp (1280 floats)
constexpr size_t OFF_H1  = ((size_t)34 << 20) + 32768;  // h1 raw (16MB)
constexpr size_t OFF_H2  = ((size_t)50 << 20) + 32768;  // h2 raw (16MB)
}

// ---------------- KNN ----------------
// Top-16 in 16 named register pairs, maintained with a FULLY BRANCH-FREE
// insert: the wave's 64 lanes are 64 different queries sharing one candidate
// stream, so "any lane inserts" ~= always -> a branch only creates a cold
// block the compiler spills around (round-2 VGPR_Count=24, VALUBusy=29%).
// Unconditional cndmask ripple is a no-op when the list is already sorted.
// Distances use __fmul_rn/__fadd_rn (no FMA contraction) to match numpy's
// elementwise rounding; strict '<' == stable top_k tie-break.

#define KNN_DECL16                                                          \
  float d0=FLT_MAX,d1=FLT_MAX,d2=FLT_MAX,d3=FLT_MAX,d4=FLT_MAX,d5=FLT_MAX, \
        d6=FLT_MAX,d7=FLT_MAX,d8=FLT_MAX,d9=FLT_MAX,d10=FLT_MAX,           \
        d11=FLT_MAX,d12=FLT_MAX,d13=FLT_MAX,d14=FLT_MAX,d15=FLT_MAX;       \
  int j0=0x7fffffff,j1=0x7fffffff,j2=0x7fffffff,j3=0x7fffffff,             \
      j4=0x7fffffff,j5=0x7fffffff,j6=0x7fffffff,j7=0x7fffffff,             \
      j8=0x7fffffff,j9=0x7fffffff,j10=0x7fffffff,j11=0x7fffffff,           \
      j12=0x7fffffff,j13=0x7fffffff,j14=0x7fffffff,j15=0x7fffffff;

// plain-distance conditional swap (stable for ties: strict <)
#define KSTEP(A,B) {                                                        \
  const bool sw = d##A < d##B;                                              \
  const float ta = sw ? d##B : d##A, tb = sw ? d##A : d##B;                 \
  const int   ua = sw ? j##B : j##A, ub = sw ? j##A : j##B;                 \
  d##A = ta; d##B = tb; j##A = ua; j##B = ub; }

// lexicographic (d, idx) conditional swap for the merge
#define MSTEP(A,B) {                                                        \
  const bool sw = (d##A < d##B) || (d##A == d##B && j##A < j##B);           \
  const float ta = sw ? d##B : d##A, tb = sw ? d##A : d##B;                 \
  const int   ua = sw ? j##B : j##A, ub = sw ? j##A : j##B;                 \
  d##A = ta; d##B = tb; j##A = ua; j##B = ub; }

#define RIPPLE(STEP)                                                        \
  STEP(15,14) STEP(14,13) STEP(13,12) STEP(12,11) STEP(11,10) STEP(10,9)    \
  STEP(9,8) STEP(8,7) STEP(7,6) STEP(6,5) STEP(5,4) STEP(4,3) STEP(3,2)     \
  STEP(2,1) STEP(1,0)

__global__ __launch_bounds__(256, 4) void knn_chunk_kernel(const float* __restrict__ xyz,
                                                           float* __restrict__ pd,
                                                           int* __restrict__ pj) {
  const int b = blockIdx.z;
  const int ch = blockIdx.y;
  const int n = blockIdx.x * 256 + threadIdx.x;
  __shared__ __align__(16) float4 tile[CAND];
  const float* xb = xyz + (size_t)b * Nq * 3;
  for (int t = threadIdx.x; t < CAND; t += 256) {
    const int j = ch * CAND + t;
    tile[t] = make_float4(xb[j * 3], xb[j * 3 + 1], xb[j * 3 + 2], 0.f);
  }
  __syncthreads();
  const float qx = xb[n * 3], qy = xb[n * 3 + 1], qz = xb[n * 3 + 2];
  KNN_DECL16;
  for (int t = 0; t < CAND; ++t) {
    const float4 c = tile[t];
    const float dx = qx - c.x, dy = qy - c.y, dz = qz - c.z;
    const float d = __fadd_rn(__fadd_rn(__fmul_rn(dx, dx), __fmul_rn(dy, dy)), __fmul_rn(dz, dz));
    // branch-free insert: replace slot 15 if smaller, then ripple (no-op if not)
    const bool ins = d < d15;
    d15 = ins ? d : d15;
    j15 = ins ? (ch * CAND + t) : j15;
    RIPPLE(KSTEP)
  }
  const size_t base = (((size_t)b * Nq + n) * CH + ch) * Kq;
  pd[base+0]=d0;  pd[base+1]=d1;  pd[base+2]=d2;  pd[base+3]=d3;
  pd[base+4]=d4;  pd[base+5]=d5;  pd[base+6]=d6;  pd[base+7]=d7;
  pd[base+8]=d8;  pd[base+9]=d9;  pd[base+10]=d10; pd[base+11]=d11;
  pd[base+12]=d12; pd[base+13]=d13; pd[base+14]=d14; pd[base+15]=d15;
  pj[base+0]=j0;  pj[base+1]=j1;  pj[base+2]=j2;  pj[base+3]=j3;
  pj[base+4]=j4;  pj[base+5]=j5;  pj[base+6]=j6;  pj[base+7]=j7;
  pj[base+8]=j8;  pj[base+9]=j9;  pj[base+10]=j10; pj[base+11]=j11;
  pj[base+12]=j12; pj[base+13]=j13; pj[base+14]=j14; pj[base+15]=j15;
}

// Merge the 8 partial lists (lexicographic (d, idx) order == jax top_k tie-break).
__global__ __launch_bounds__(256, 4) void knn_merge_kernel(const float* __restrict__ pd,
                                                           const int* __restrict__ pj,
                                                           int* __restrict__ idxo) {
  const int q = blockIdx.x * 256 + threadIdx.x;
  KNN_DECL16;
  const size_t base = (size_t)q * CH * Kq;
  for (int t = 0; t < CH * Kq; ++t) {
    const float d = pd[base + t];
    const int j = pj[base + t];
    const bool ins = (d < d15) || (d == d15 && j < j15);
    d15 = ins ? d : d15;
    j15 = ins ? j : j15;
    RIPPLE(MSTEP)
  }
  int* op = idxo + (size_t)q * Kq;
  op[0]=j0;  op[1]=j1;  op[2]=j2;  op[3]=j3;
  op[4]=j4;  op[5]=j5;  op[6]=j6;  op[7]=j7;
  op[8]=j8;  op[9]=j9;  op[10]=j10; op[11]=j11;
  op[12]=j12; op[13]=j13; op[14]=j14; op[15]=j15;
}

// ---------------- enc builder (one wave, one point) ----------------
// enc row layout: [rel.x rel.y rel.z dist f0..f31] padded to 40 floats.
DEVFN void build_enc(const float* __restrict__ xb, const float* __restrict__ fb,
                     const int* __restrict__ idxp, int n, int lane, float* enc) {
  const int k = lane >> 2, sub = lane & 3;
  const int j = idxp[k];
  const float* fr = fb + (size_t)j * Cq;
  float* er = enc + k * 40;
  const float4 f0 = *(const float4*)(fr + sub * 8);
  const float4 f1 = *(const float4*)(fr + sub * 8 + 4);
  *(float4*)(er + 4 + sub * 8) = f0;
  *(float4*)(er + 4 + sub * 8 + 4) = f1;
  if (sub == 0) {
    const float cx = xb[n * 3], cy = xb[n * 3 + 1], cz = xb[n * 3 + 2];
    const float rx = xb[j * 3] - cx, ry = xb[j * 3 + 1] - cy, rz = xb[j * 3 + 2] - cz;
    const float ss = rx * rx + ry * ry + rz * rz;
    er[0] = rx; er[1] = ry; er[2] = rz;
    er[3] = sqrtf(fmaxf(ss, 1e-12f));
  }
}

// ---------------- pass1: y = enc @ w_lse^T, accumulate mean/var stats ----------------
__global__ __launch_bounds__(256) void pass1_kernel(const float* __restrict__ xyz,
                                                    const float* __restrict__ features,
                                                    const int* __restrict__ idx,
                                                    const float* __restrict__ wl1,
                                                    const float* __restrict__ wl2,
                                                    double* __restrict__ dstat) {
  const int br = blockIdx.y;
  const float* W = br ? wl2 : wl1;
  __shared__ __align__(16) float wl[64 * 40];
  __shared__ __align__(16) float encS[4][16 * 40];
  for (int t = threadIdx.x; t < 64 * 36; t += 256) wl[(t / 36) * 40 + (t % 36)] = W[t];
  __syncthreads();
  const int lane = threadIdx.x & 63, wv = threadIdx.x >> 6;
  float* enc = encS[wv];
  float wreg[36];
#pragma unroll
  for (int c = 0; c < 36; ++c) wreg[c] = wl[lane * 40 + c];
  float s1 = 0.f, s2 = 0.f;
  const int wid = blockIdx.x * 4 + wv, nw = gridDim.x * 4;
  for (int p = wid; p < PTS; p += nw) {
    const int b = p >> 13, n = p & (Nq - 1);
    build_enc(xyz + (size_t)b * Nq * 3, features + (size_t)b * Nq * Cq,
              idx + (size_t)p * Kq, n, lane, enc);
    __syncthreads();
#pragma unroll
    for (int k = 0; k < 16; ++k) {
      const float* er = enc + k * 40;
      float acc = 0.f;
#pragma unroll
      for (int c = 0; c < 36; ++c) acc += er[c] * wreg[c];
      s1 += acc; s2 += acc * acc;
    }
    __syncthreads();
  }
  atomicAdd(&dstat[DS_Y + br * 64 + lane], (double)s1);
  atomicAdd(&dstat[DS_Y + 128 + br * 64 + lane], (double)s2);
}

// ---------------- generic BN stat finalize: mean + rsqrt(var+eps) ----------------
__global__ void bn_finalize_kernel(const double* __restrict__ dstat, float* __restrict__ bnp,
                                   int base, double invc) {
  const int t = threadIdx.x;  // 128 threads
  const double m = dstat[base + t] * invc;
  const double v = dstat[base + 128 + t] * invc - m * m;
  bnp[base + t] = (float)m;
  bnp[base + 128 + t] = (float)(1.0 / sqrt(v + 1e-5));
}

// ---------------- passA: x = relu(bn(y)); z = x @ sw1^T; accumulate z stats ----------------
__global__ __launch_bounds__(256) void passA_kernel(const float* __restrict__ xyz,
                                                    const float* __restrict__ features,
                                                    const int* __restrict__ idx,
                                                    const float* __restrict__ wl1,
                                                    const float* __restrict__ wl2,
                                                    const float* __restrict__ s1a,
                                                    const float* __restrict__ s1b,
                                                    const float* __restrict__ bnp,
                                                    double* __restrict__ dstat) {
  const int br = blockIdx.y;
  const float* W = br ? wl2 : wl1;
  const float* S1 = br ? s1b : s1a;
  __shared__ __align__(16) float wl[64 * 40];
  __shared__ __align__(16) float s1l[64 * 64];
  __shared__ __align__(16) float encS[4][16 * 40];
  __shared__ __align__(16) float xS[4][16 * 68];
  for (int t = threadIdx.x; t < 64 * 36; t += 256) wl[(t / 36) * 40 + (t % 36)] = W[t];
  for (int t = threadIdx.x; t < 64 * 64; t += 256) s1l[t] = S1[t];
  __syncthreads();
  const int lane = threadIdx.x & 63, wv = threadIdx.x >> 6;
  float* enc = encS[wv];
  float* xL = xS[wv];
  float wreg[36];
#pragma unroll
  for (int c = 0; c < 36; ++c) wreg[c] = wl[lane * 40 + c];
  float sreg[64];
#pragma unroll
  for (int c = 0; c < 64; ++c) sreg[c] = s1l[lane * 64 + c];
  const float ym = bnp[DS_Y + br * 64 + lane];
  const float ys = bnp[DS_Y + 128 + br * 64 + lane];
  float zs1 = 0.f, zs2 = 0.f;
  const int wid = blockIdx.x * 4 + wv, nw = gridDim.x * 4;
  for (int p = wid; p < PTS; p += nw) {
    const int b = p >> 13, n = p & (Nq - 1);
    build_enc(xyz + (size_t)b * Nq * 3, features + (size_t)b * Nq * Cq,
              idx + (size_t)p * Kq, n, lane, enc);
    __syncthreads();
#pragma unroll
    for (int k = 0; k < 16; ++k) {
      const float* er = enc + k * 40;
      float acc = 0.f;
#pragma unroll
      for (int c = 0; c < 36; ++c) acc += er[c] * wreg[c];
      float xv = (acc - ym) * ys;
      xv = xv > 0.f ? xv : 0.f;
      xL[k * 68 + lane] = xv;
    }
    __syncthreads();
#pragma unroll
    for (int k = 0; k < 16; ++k) {
      float acc = 0.f;
#pragma unroll
      for (int c = 0; c < 64; ++c) acc += xL[k * 68 + c] * sreg[c];
      zs1 += acc; zs2 += acc * acc;
    }
    __syncthreads();
  }
  atomicAdd(&dstat[DS_Z + br * 64 + lane], (double)zs1);
  atomicAdd(&dstat[DS_Z + 128 + br * 64 + lane], (double)zs2);
}

// ---------------- passB: full branch -> g = feat @ mw^T raw; accumulate g stats ----------------
__global__ __launch_bounds__(256) void passB_kernel(const float* __restrict__ xyz,
                                                    const float* __restrict__ features,
                                                    const int* __restrict__ idx,
                                                    const float* __restrict__ wl1,
                                                    const float* __restrict__ wl2,
                                                    const float* __restrict__ s1a,
                                                    const float* __restrict__ s1b,
                                                    const float* __restrict__ s2a,
                                                    const float* __restrict__ s2b,
                                                    const float* __restrict__ sba,
                                                    const float* __restrict__ sbb,
                                                    const float* __restrict__ mwa,
                                                    const float* __restrict__ mwb,
                                                    const float* __restrict__ bnp,
                                                    double* __restrict__ dstat,
                                                    float* __restrict__ graw) {
  const int br = blockIdx.y;
  const float* W = br ? wl2 : wl1;
  const float* S1 = br ? s1b : s1a;
  const float* S2 = br ? s2b : s2a;
  const float* SB = br ? sbb : sba;
  const float* MW = br ? mwb : mwa;
  __shared__ __align__(16) float wl[64 * 40];
  __shared__ __align__(16) float s1l[64 * 64];
  __shared__ __align__(16) float mwl[64 * 65];
  __shared__ __align__(16) float encS[4][16 * 40];
  __shared__ __align__(16) float xS[4][16 * 68];
  __shared__ __align__(16) float featL[4][64];
  for (int t = threadIdx.x; t < 64 * 36; t += 256) wl[(t / 36) * 40 + (t % 36)] = W[t];
  for (int t = threadIdx.x; t < 64 * 64; t += 256) s1l[t] = S1[t];
  for (int t = threadIdx.x; t < 64 * 64; t += 256) mwl[(t >> 6) * 65 + (t & 63)] = MW[t];
  __syncthreads();
  const int lane = threadIdx.x & 63, wv = threadIdx.x >> 6;
  float* enc = encS[wv];
  float* xL = xS[wv];
  float wreg[36];
#pragma unroll
  for (int c = 0; c < 36; ++c) wreg[c] = wl[lane * 40 + c];
  float sreg[64];
#pragma unroll
  for (int c = 0; c < 64; ++c) sreg[c] = s1l[lane * 64 + c];
  const float ym = bnp[DS_Y + br * 64 + lane];
  const float ys = bnp[DS_Y + 128 + br * 64 + lane];
  const float zm = bnp[DS_Z + br * 64 + lane];
  const float zs = bnp[DS_Z + 128 + br * 64 + lane];
  const float sw2r = S2[lane];
  const float sb2v = SB[0];
  float gs1 = 0.f, gs2 = 0.f;
  const int wid = blockIdx.x * 4 + wv, nw = gridDim.x * 4;
  for (int p = wid; p < PTS; p += nw) {
    const int b = p >> 13, n = p & (Nq - 1);
    build_enc(xyz + (size_t)b * Nq * 3, features + (size_t)b * Nq * Cq,
              idx + (size_t)p * Kq, n, lane, enc);
    __syncthreads();
    float xr[16];
#pragma unroll
    for (int k = 0; k < 16; ++k) {
      const float* er = enc + k * 40;
      float acc = 0.f;
#pragma unroll
      for (int c = 0; c < 36; ++c) acc += er[c] * wreg[c];
      float xv = (acc - ym) * ys;
      xv = xv > 0.f ? xv : 0.f;
      xr[k] = xv;
      xL[k * 68 + lane] = xv;
    }
    __syncthreads();
    float pl[16];
#pragma unroll
    for (int k = 0; k < 16; ++k) {
      float acc = 0.f;
#pragma unroll
      for (int c = 0; c < 64; ++c) acc += xL[k * 68 + c] * sreg[c];
      float h = (acc - zm) * zs;
      h = h > 0.f ? h : 0.f;
      pl[k] = h * sw2r;
    }
    // wave-wide sum over 64 lanes (channel dim) for the 16 logits
#pragma unroll
    for (int off = 1; off < 64; off <<= 1) {
#pragma unroll
      for (int k = 0; k < 16; ++k) pl[k] += __shfl_xor(pl[k], off, 64);
    }
    float lg[16];
    float mx = -FLT_MAX;
#pragma unroll
    for (int k = 0; k < 16; ++k) { lg[k] = pl[k] + sb2v; mx = fmaxf(mx, lg[k]); }
    float se = 0.f;
#pragma unroll
    for (int k = 0; k < 16; ++k) { lg[k] = expf(lg[k] - mx); se += lg[k]; }
    const float inv = 1.f / se;
    float f = 0.f;
#pragma unroll
    for (int k = 0; k < 16; ++k) f += xr[k] * (lg[k] * inv);
    featL[wv][lane] = f;
    __syncthreads();
    float g = 0.f;
#pragma unroll
    for (int c = 0; c < 64; ++c) g += featL[wv][c] * mwl[lane * 65 + c];
    graw[((size_t)br * PTS + p) * 64 + lane] = g;
    gs1 += g; gs2 += g * g;
    __syncthreads();
  }
  atomicAdd(&dstat[DS_G + br * 64 + lane], (double)gs1);
  atomicAdd(&dstat[DS_G + 128 + br * 64 + lane], (double)gs2);
}

// ---------------- DRB matmul stage (128x128 per-point matvec + stats) ----------------
__global__ __launch_bounds__(256) void drb_mm_kernel(const float* __restrict__ in,
                                                     const float* __restrict__ wmat,
                                                     const float* __restrict__ bnp,
                                                     double* __restrict__ dstat,
                                                     float* __restrict__ aggout,
                                                     float* __restrict__ rowout,
                                                     int bpIn, int dsOut, int mode) {
  __shared__ __align__(16) float wlds[128 * 129];
  __shared__ __align__(16) float rowS[4][128];
  for (int t = threadIdx.x; t < 128 * 128; t += 256) wlds[(t >> 7) * 129 + (t & 127)] = wmat[t];
  __syncthreads();
  const int lane = threadIdx.x & 63, wv = threadIdx.x >> 6;
  const float m0 = bnp[bpIn + lane], s0 = bnp[bpIn + 128 + lane];
  const float m1 = bnp[bpIn + 64 + lane], s1 = bnp[bpIn + 128 + 64 + lane];
  float a1s0 = 0.f, a1s1 = 0.f, a2s0 = 0.f, a2s1 = 0.f;
  const int wid = blockIdx.x * 4 + wv, nw = gridDim.x * 4;
  for (int p = wid; p < PTS; p += nw) {
    float v0, v1;
    if (mode == 0) {  // input = g_raw [2][PTS][64]
      v0 = in[(size_t)p * 64 + lane];
      v1 = in[(size_t)PTS * 64 + (size_t)p * 64 + lane];
    } else {          // input = h1 raw [PTS][128]
      v0 = in[(size_t)p * 128 + lane];
      v1 = in[(size_t)p * 128 + 64 + lane];
    }
    v0 = (v0 - m0) * s0; v0 = v0 > 0.f ? v0 : 0.f;
    v1 = (v1 - m1) * s1; v1 = v1 > 0.f ? v1 : 0.f;
    rowS[wv][lane] = v0;
    rowS[wv][64 + lane] = v1;
    if (aggout) {
      aggout[(size_t)p * 128 + lane] = v0;
      aggout[(size_t)p * 128 + 64 + lane] = v1;
    }
    __syncthreads();
#pragma unroll
    for (int h = 0; h < 2; ++h) {
      const int o = h * 64 + lane;
      float acc = 0.f;
#pragma unroll
      for (int c = 0; c < 128; ++c) acc += rowS[wv][c] * wlds[o * 129 + c];
      rowout[(size_t)p * 128 + o] = acc;
      if (h == 0) { a1s0 += acc; a2s0 += acc * acc; }
      else        { a1s1 += acc; a2s1 += acc * acc; }
    }
    __syncthreads();
  }
  atomicAdd(&dstat[dsOut + lane], (double)a1s0);
  atomicAdd(&dstat[dsOut + 64 + lane], (double)a1s1);
  atomicAdd(&dstat[dsOut + 128 + lane], (double)a2s0);
  atomicAdd(&dstat[dsOut + 128 + 64 + lane], (double)a2s1);
}

// ---------------- final: out = relu(bn(h2) + agg) ----------------
__global__ __launch_bounds__(256) void final_kernel(const float* __restrict__ h2,
                                                    const float* __restrict__ agg,
                                                    const float* __restrict__ bnp,
                                                    float* __restrict__ out) {
  const size_t e = (size_t)blockIdx.x * 256 + threadIdx.x;
  const int ch = (int)(e & 127);
  const float m = bnp[DS_H2 + ch], s = bnp[DS_H2 + 128 + ch];
  float v = (h2[e] - m) * s + agg[e];
  out[e] = v > 0.f ? v : 0.f;
}

extern "C" void kernel_launch(void* const* d_in, const int* in_sizes, int n_in,
                              void* d_out, int out_size, void* d_ws, size_t ws_size,
                              hipStream_t stream) {
  (void)in_sizes; (void)n_in; (void)out_size; (void)ws_size;
  const float* xyz      = (const float*)d_in[0];
  const float* features = (const float*)d_in[1];
  const float* w_lse1   = (const float*)d_in[2];
  const float* w_lse2   = (const float*)d_in[3];
  const float* ap1_sw1  = (const float*)d_in[4];
  const float* ap1_sw2  = (const float*)d_in[5];
  const float* ap1_sb2  = (const float*)d_in[6];
  const float* ap1_mw   = (const float*)d_in[7];
  const float* ap2_sw1  = (const float*)d_in[8];
  const float* ap2_sw2  = (const float*)d_in[9];
  const float* ap2_sb2  = (const float*)d_in[10];
  const float* ap2_mw   = (const float*)d_in[11];
  const float* drb_w1   = (const float*)d_in[12];
  const float* drb_w2   = (const float*)d_in[13];

  char* ws = (char*)d_ws;
  float*  knn_d = (float*)(ws + OFF_A);
  int*    knn_j = (int*)(ws + OFF_B);
  int*    idx   = (int*)(ws + OFF_IDX);
  double* dstat = (double*)(ws + OFF_DST);
  float*  bnp   = (float*)(ws + OFF_BNP);
  float*  graw  = (float*)(ws + OFF_A);   // reuse after knn done
  float*  agg   = (float*)(ws + OFF_B);   // reuse after knn done
  float*  h1    = (float*)(ws + OFF_H1);
  float*  h2    = (float*)(ws + OFF_H2);
  float*  out   = (float*)d_out;

  hipMemsetAsync(dstat, 0, 1280 * sizeof(double), stream);

  knn_chunk_kernel<<<dim3(Nq / 256, CH, Bq), 256, 0, stream>>>(xyz, knn_d, knn_j);
  knn_merge_kernel<<<dim3(PTS / 256), 256, 0, stream>>>(knn_d, knn_j, idx);

  pass1_kernel<<<dim3(512, 2), 256, 0, stream>>>(xyz, features, idx, w_lse1, w_lse2, dstat);
  bn_finalize_kernel<<<1, 128, 0, stream>>>(dstat, bnp, DS_Y, 1.0 / ROWS);

  passA_kernel<<<dim3(256, 2), 256, 0, stream>>>(xyz, features, idx, w_lse1, w_lse2,
                                                 ap1_sw1, ap2_sw1, bnp, dstat);
  bn_finalize_kernel<<<1, 128, 0, stream>>>(dstat, bnp, DS_Z, 1.0 / ROWS);

  passB_kernel<<<dim3(256, 2), 256, 0, stream>>>(xyz, features, idx, w_lse1, w_lse2,
                                                 ap1_sw1, ap2_sw1, ap1_sw2, ap2_sw2,
                                                 ap1_sb2, ap2_sb2, ap1_mw, ap2_mw,
                                                 bnp, dstat, graw);
  bn_finalize_kernel<<<1, 128, 0, stream>>>(dstat, bnp, DS_G, 1.0 / PTS);

  drb_mm_kernel<<<dim3(256), 256, 0, stream>>>(graw, drb_w1, bnp, dstat, agg, h1,
                                               DS_G, DS_H1, 0);
  bn_finalize_kernel<<<1, 128, 0, stream>>>(dstat, bnp, DS_H1, 1.0 / PTS);

  drb_mm_kernel<<<dim3(256), 256, 0, stream>>>(h1, drb_w2, bnp, dstat, nullptr, h2,
                                               DS_H1, DS_H2, 1);
  bn_finalize_kernel<<<1, 128, 0, stream>>>(dstat, bnp, DS_H2, 1.0 / PTS);

  final_kernel<<<dim3(PTS * 128 / 256), 256, 0, stream>>>(h2, agg, bnp, out);
}

// Round 4
// 2685.579 us; speedup vs baseline: 1.5248x; 1.5248x over previous
//
#include <hip/hip_runtime.h>
#include <hip/hip_bf16.h>
#include <float.h>
#include <math.h>

#define DEVFN __device__ __forceinline__

namespace {
constexpr int Bq = 4, Nq = 8192, Cq = 32, Kq = 16;
constexpr int PTS = Bq * Nq;          // 32768 points
constexpr int CH = 8;                  // knn candidate chunks
constexpr int CAND = Nq / CH;          // 1024 candidates per chunk
constexpr double ROWS = 524288.0;      // PTS * Kq

// stat/bnp region bases (each region: [sum|mean x128][sumsq|scale x128])
constexpr int DS_Y = 0, DS_Z = 256, DS_G = 512, DS_H1 = 768, DS_H2 = 1024;

// workspace byte offsets
constexpr size_t OFF_A   = 0;                         // knn_d (16MB) -> reused as g_raw
constexpr size_t OFF_B   = (size_t)16 << 20;          // knn_j (16MB) -> reused as agg
constexpr size_t OFF_IDX = (size_t)32 << 20;          // idx (2MB)
constexpr size_t OFF_DST = (size_t)34 << 20;          // dstat (1280 doubles)
constexpr size_t OFF_BNP = ((size_t)34 << 20) + 16384;  // bnp (1280 floats)
constexpr size_t OFF_H1  = ((size_t)34 << 20) + 32768;  // h1 raw (16MB)
constexpr size_t OFF_H2  = ((size_t)50 << 20) + 32768;  // h2 raw (16MB)
}

// ---------------- KNN: two-phase select-then-collect ----------------
// Round-3 evidence: compiler keeps 16 float distances in VGPRs but demotes the
// 16 index regs to scratch (VGPR_Count=24). So the hot scan keeps ONLY the 16
// smallest distances via a min/max insertion network (no indices, no compares),
// then cheap re-scans collect the indices:
//   2a: all d <  kth  (<=15 of them, ascending index order)
//   2b: d == kth while cnt<16 (ascending index = stable top_k tie-break)
// Distance recompute is bit-identical (__fmul_rn/__fadd_rn, non-contractable).

#define TOP16_DECL                                                           \
  float e0=FLT_MAX,e1=FLT_MAX,e2=FLT_MAX,e3=FLT_MAX,e4=FLT_MAX,e5=FLT_MAX,  \
        e6=FLT_MAX,e7=FLT_MAX,e8=FLT_MAX,e9=FLT_MAX,e10=FLT_MAX,            \
        e11=FLT_MAX,e12=FLT_MAX,e13=FLT_MAX,e14=FLT_MAX,e15=FLT_MAX;

#define TINS(i) { const float lo = fminf(e##i, u); u = fmaxf(e##i, u); e##i = lo; }
#define TINS_ALL  TINS(0) TINS(1) TINS(2) TINS(3) TINS(4) TINS(5) TINS(6)    \
                  TINS(7) TINS(8) TINS(9) TINS(10) TINS(11) TINS(12)         \
                  TINS(13) TINS(14) TINS(15)

DEVFN float distf(const float4 c, const float qx, const float qy, const float qz) {
  const float dx = qx - c.x, dy = qy - c.y, dz = qz - c.z;
  return __fadd_rn(__fadd_rn(__fmul_rn(dx, dx), __fmul_rn(dy, dy)), __fmul_rn(dz, dz));
}

__global__ __launch_bounds__(256, 4) void knn_chunk_kernel(const float* __restrict__ xyz,
                                                           float* __restrict__ pd,
                                                           int* __restrict__ pj) {
  const int b = blockIdx.z;
  const int ch = blockIdx.y;
  const int n = blockIdx.x * 256 + threadIdx.x;
  __shared__ __align__(16) float4 tile[CAND];
  const float* xb = xyz + (size_t)b * Nq * 3;
  for (int t = threadIdx.x; t < CAND; t += 256) {
    const int j = ch * CAND + t;
    tile[t] = make_float4(xb[j * 3], xb[j * 3 + 1], xb[j * 3 + 2], 0.f);
  }
  __syncthreads();
  const float qx = xb[n * 3], qy = xb[n * 3 + 1], qz = xb[n * 3 + 2];
  // scan 1: 16 smallest distances (values only)
  TOP16_DECL;
  for (int t = 0; t < CAND; ++t) {
    float u = distf(tile[t], qx, qy, qz);
    TINS_ALL
  }
  const float kth = e15;
  // scan 2a: collect indices with d < kth (ascending index order)
  const size_t base = (((size_t)b * Nq + n) * CH + ch) * Kq;
  int cnt = 0;
  for (int t = 0; t < CAND; ++t) {
    const float d = distf(tile[t], qx, qy, qz);
    if (d < kth) { pd[base + cnt] = d; pj[base + cnt] = ch * CAND + t; ++cnt; }
  }
  // scan 2b: fill remaining slots with ties (d == kth), lowest index first
  for (int t = 0; t < CAND; ++t) {
    const float d = distf(tile[t], qx, qy, qz);
    if (d == kth && cnt < 16) { pd[base + cnt] = d; pj[base + cnt] = ch * CAND + t; ++cnt; }
  }
}

// Merge the 8 partial lists. Chunk lists are in ascending global-index order
// and chunks cover ascending index ranges -> the 128-entry scan is in
// ascending index order, so the same two-phase collect is a stable top_k.
__global__ __launch_bounds__(256, 4) void knn_merge_kernel(const float* __restrict__ pd,
                                                           const int* __restrict__ pj,
                                                           int* __restrict__ idxo) {
  const int q = blockIdx.x * 256 + threadIdx.x;
  const float* dp = pd + (size_t)q * CH * Kq;
  const int* jp = pj + (size_t)q * CH * Kq;
  TOP16_DECL;
  for (int t = 0; t < CH * Kq; t += 4) {
    const float4 v = *(const float4*)(dp + t);
    { float u = v.x; TINS_ALL }
    { float u = v.y; TINS_ALL }
    { float u = v.z; TINS_ALL }
    { float u = v.w; TINS_ALL }
  }
  const float kth = e15;
  int* op = idxo + (size_t)q * Kq;
  int cnt = 0;
  for (int t = 0; t < CH * Kq; ++t) {
    const float d = dp[t];
    if (d < kth) { op[cnt] = jp[t]; ++cnt; }
  }
  for (int t = 0; t < CH * Kq; ++t) {
    const float d = dp[t];
    if (d == kth && cnt < 16) { op[cnt] = jp[t]; ++cnt; }
  }
}

// ---------------- enc builder (one wave, one point) ----------------
// enc row layout: [rel.x rel.y rel.z dist f0..f31] padded to 40 floats.
DEVFN void build_enc(const float* __restrict__ xb, const float* __restrict__ fb,
                     const int* __restrict__ idxp, int n, int lane, float* enc) {
  const int k = lane >> 2, sub = lane & 3;
  const int j = idxp[k];
  const float* fr = fb + (size_t)j * Cq;
  float* er = enc + k * 40;
  const float4 f0 = *(const float4*)(fr + sub * 8);
  const float4 f1 = *(const float4*)(fr + sub * 8 + 4);
  *(float4*)(er + 4 + sub * 8) = f0;
  *(float4*)(er + 4 + sub * 8 + 4) = f1;
  if (sub == 0) {
    const float cx = xb[n * 3], cy = xb[n * 3 + 1], cz = xb[n * 3 + 2];
    const float rx = xb[j * 3] - cx, ry = xb[j * 3 + 1] - cy, rz = xb[j * 3 + 2] - cz;
    const float ss = rx * rx + ry * ry + rz * rz;
    er[0] = rx; er[1] = ry; er[2] = rz;
    er[3] = sqrtf(fmaxf(ss, 1e-12f));
  }
}

// ---------------- pass1: y = enc @ w_lse^T, accumulate mean/var stats ----------------
// Weights loaded straight from global into registers (L2-hot, one-time):
// the old LDS staging pattern wl[lane*40+c] was an 8-way bank conflict and
// s1l[lane*64+c] a 64-way conflict (round-3 SQ_LDS_BANK_CONFLICT=3.9M).
__global__ __launch_bounds__(256) void pass1_kernel(const float* __restrict__ xyz,
                                                    const float* __restrict__ features,
                                                    const int* __restrict__ idx,
                                                    const float* __restrict__ wl1,
                                                    const float* __restrict__ wl2,
                                                    double* __restrict__ dstat) {
  const int br = blockIdx.y;
  const float* W = br ? wl2 : wl1;
  __shared__ __align__(16) float encS[4][16 * 40];
  const int lane = threadIdx.x & 63, wv = threadIdx.x >> 6;
  float* enc = encS[wv];
  float wreg[36];
#pragma unroll
  for (int c = 0; c < 36; ++c) wreg[c] = W[lane * 36 + c];
  float s1 = 0.f, s2 = 0.f;
  const int wid = blockIdx.x * 4 + wv, nw = gridDim.x * 4;
  for (int p = wid; p < PTS; p += nw) {
    const int b = p >> 13, n = p & (Nq - 1);
    build_enc(xyz + (size_t)b * Nq * 3, features + (size_t)b * Nq * Cq,
              idx + (size_t)p * Kq, n, lane, enc);
    __syncthreads();
#pragma unroll
    for (int k = 0; k < 16; ++k) {
      const float* er = enc + k * 40;
      float acc = 0.f;
#pragma unroll
      for (int c = 0; c < 36; ++c) acc += er[c] * wreg[c];
      s1 += acc; s2 += acc * acc;
    }
    __syncthreads();
  }
  atomicAdd(&dstat[DS_Y + br * 64 + lane], (double)s1);
  atomicAdd(&dstat[DS_Y + 128 + br * 64 + lane], (double)s2);
}

// ---------------- generic BN stat finalize: mean + rsqrt(var+eps) ----------------
__global__ void bn_finalize_kernel(const double* __restrict__ dstat, float* __restrict__ bnp,
                                   int base, double invc) {
  const int t = threadIdx.x;  // 128 threads
  const double m = dstat[base + t] * invc;
  const double v = dstat[base + 128 + t] * invc - m * m;
  bnp[base + t] = (float)m;
  bnp[base + 128 + t] = (float)(1.0 / sqrt(v + 1e-5));
}

// ---------------- passA: x = relu(bn(y)); z = x @ sw1^T; accumulate z stats ----------------
__global__ __launch_bounds__(256) void passA_kernel(const float* __restrict__ xyz,
                                                    const float* __restrict__ features,
                                                    const int* __restrict__ idx,
                                                    const float* __restrict__ wl1,
                                                    const float* __restrict__ wl2,
                                                    const float* __restrict__ s1a,
                                                    const float* __restrict__ s1b,
                                                    const float* __restrict__ bnp,
                                                    double* __restrict__ dstat) {
  const int br = blockIdx.y;
  const float* W = br ? wl2 : wl1;
  const float* S1 = br ? s1b : s1a;
  __shared__ __align__(16) float encS[4][16 * 40];
  __shared__ __align__(16) float xS[4][16 * 68];
  const int lane = threadIdx.x & 63, wv = threadIdx.x >> 6;
  float* enc = encS[wv];
  float* xL = xS[wv];
  float wreg[36];
#pragma unroll
  for (int c = 0; c < 36; ++c) wreg[c] = W[lane * 36 + c];
  float sreg[64];
#pragma unroll
  for (int c = 0; c < 64; ++c) sreg[c] = S1[lane * 64 + c];
  const float ym = bnp[DS_Y + br * 64 + lane];
  const float ys = bnp[DS_Y + 128 + br * 64 + lane];
  float zs1 = 0.f, zs2 = 0.f;
  const int wid = blockIdx.x * 4 + wv, nw = gridDim.x * 4;
  for (int p = wid; p < PTS; p += nw) {
    const int b = p >> 13, n = p & (Nq - 1);
    build_enc(xyz + (size_t)b * Nq * 3, features + (size_t)b * Nq * Cq,
              idx + (size_t)p * Kq, n, lane, enc);
    __syncthreads();
#pragma unroll
    for (int k = 0; k < 16; ++k) {
      const float* er = enc + k * 40;
      float acc = 0.f;
#pragma unroll
      for (int c = 0; c < 36; ++c) acc += er[c] * wreg[c];
      float xv = (acc - ym) * ys;
      xv = xv > 0.f ? xv : 0.f;
      xL[k * 68 + lane] = xv;
    }
    __syncthreads();
#pragma unroll
    for (int k = 0; k < 16; ++k) {
      float acc = 0.f;
#pragma unroll
      for (int c = 0; c < 64; ++c) acc += xL[k * 68 + c] * sreg[c];
      zs1 += acc; zs2 += acc * acc;
    }
    __syncthreads();
  }
  atomicAdd(&dstat[DS_Z + br * 64 + lane], (double)zs1);
  atomicAdd(&dstat[DS_Z + 128 + br * 64 + lane], (double)zs2);
}

// ---------------- passB: full branch -> g = feat @ mw^T raw; accumulate g stats ----------------
__global__ __launch_bounds__(256) void passB_kernel(const float* __restrict__ xyz,
                                                    const float* __restrict__ features,
                                                    const int* __restrict__ idx,
                                                    const float* __restrict__ wl1,
                                                    const float* __restrict__ wl2,
                                                    const float* __restrict__ s1a,
                                                    const float* __restrict__ s1b,
                                                    const float* __restrict__ s2a,
                                                    const float* __restrict__ s2b,
                                                    const float* __restrict__ sba,
                                                    const float* __restrict__ sbb,
                                                    const float* __restrict__ mwa,
                                                    const float* __restrict__ mwb,
                                                    const float* __restrict__ bnp,
                                                    double* __restrict__ dstat,
                                                    float* __restrict__ graw) {
  const int br = blockIdx.y;
  const float* W = br ? wl2 : wl1;
  const float* S1 = br ? s1b : s1a;
  const float* S2 = br ? s2b : s2a;
  const float* SB = br ? sbb : sba;
  const float* MW = br ? mwb : mwa;
  __shared__ __align__(16) float mwl[64 * 65];
  __shared__ __align__(16) float encS[4][16 * 40];
  __shared__ __align__(16) float xS[4][16 * 68];
  __shared__ __align__(16) float featL[4][64];
  for (int t = threadIdx.x; t < 64 * 64; t += 256) mwl[(t >> 6) * 65 + (t & 63)] = MW[t];
  __syncthreads();
  const int lane = threadIdx.x & 63, wv = threadIdx.x >> 6;
  float* enc = encS[wv];
  float* xL = xS[wv];
  float wreg[36];
#pragma unroll
  for (int c = 0; c < 36; ++c) wreg[c] = W[lane * 36 + c];
  float sreg[64];
#pragma unroll
  for (int c = 0; c < 64; ++c) sreg[c] = S1[lane * 64 + c];
  const float ym = bnp[DS_Y + br * 64 + lane];
  const float ys = bnp[DS_Y + 128 + br * 64 + lane];
  const float zm = bnp[DS_Z + br * 64 + lane];
  const float zs = bnp[DS_Z + 128 + br * 64 + lane];
  const float sw2r = S2[lane];
  const float sb2v = SB[0];
  float gs1 = 0.f, gs2 = 0.f;
  const int wid = blockIdx.x * 4 + wv, nw = gridDim.x * 4;
  for (int p = wid; p < PTS; p += nw) {
    const int b = p >> 13, n = p & (Nq - 1);
    build_enc(xyz + (size_t)b * Nq * 3, features + (size_t)b * Nq * Cq,
              idx + (size_t)p * Kq, n, lane, enc);
    __syncthreads();
    float xr[16];
#pragma unroll
    for (int k = 0; k < 16; ++k) {
      const float* er = enc + k * 40;
      float acc = 0.f;
#pragma unroll
      for (int c = 0; c < 36; ++c) acc += er[c] * wreg[c];
      float xv = (acc - ym) * ys;
      xv = xv > 0.f ? xv : 0.f;
      xr[k] = xv;
      xL[k * 68 + lane] = xv;
    }
    __syncthreads();
    float pl[16];
#pragma unroll
    for (int k = 0; k < 16; ++k) {
      float acc = 0.f;
#pragma unroll
      for (int c = 0; c < 64; ++c) acc += xL[k * 68 + c] * sreg[c];
      float h = (acc - zm) * zs;
      h = h > 0.f ? h : 0.f;
      pl[k] = h * sw2r;
    }
    // wave-wide sum over 64 lanes (channel dim) for the 16 logits
#pragma unroll
    for (int off = 1; off < 64; off <<= 1) {
#pragma unroll
      for (int k = 0; k < 16; ++k) pl[k] += __shfl_xor(pl[k], off, 64);
    }
    float lg[16];
    float mx = -FLT_MAX;
#pragma unroll
    for (int k = 0; k < 16; ++k) { lg[k] = pl[k] + sb2v; mx = fmaxf(mx, lg[k]); }
    float se = 0.f;
#pragma unroll
    for (int k = 0; k < 16; ++k) { lg[k] = expf(lg[k] - mx); se += lg[k]; }
    const float inv = 1.f / se;
    float f = 0.f;
#pragma unroll
    for (int k = 0; k < 16; ++k) f += xr[k] * (lg[k] * inv);
    featL[wv][lane] = f;
    __syncthreads();
    float g = 0.f;
#pragma unroll
    for (int c = 0; c < 64; ++c) g += featL[wv][c] * mwl[lane * 65 + c];
    graw[((size_t)br * PTS + p) * 64 + lane] = g;
    gs1 += g; gs2 += g * g;
    __syncthreads();
  }
  atomicAdd(&dstat[DS_G + br * 64 + lane], (double)gs1);
  atomicAdd(&dstat[DS_G + 128 + br * 64 + lane], (double)gs2);
}

// ---------------- DRB matmul stage (128x128 per-point matvec + stats) ----------------
__global__ __launch_bounds__(256) void drb_mm_kernel(const float* __restrict__ in,
                                                     const float* __restrict__ wmat,
                                                     const float* __restrict__ bnp,
                                                     double* __restrict__ dstat,
                                                     float* __restrict__ aggout,
                                                     float* __restrict__ rowout,
                                                     int bpIn, int dsOut, int mode) {
  __shared__ __align__(16) float wlds[128 * 129];
  __shared__ __align__(16) float rowS[4][128];
  for (int t = threadIdx.x; t < 128 * 128; t += 256) wlds[(t >> 7) * 129 + (t & 127)] = wmat[t];
  __syncthreads();
  const int lane = threadIdx.x & 63, wv = threadIdx.x >> 6;
  const float m0 = bnp[bpIn + lane], s0 = bnp[bpIn + 128 + lane];
  const float m1 = bnp[bpIn + 64 + lane], s1 = bnp[bpIn + 128 + 64 + lane];
  float a1s0 = 0.f, a1s1 = 0.f, a2s0 = 0.f, a2s1 = 0.f;
  const int wid = blockIdx.x * 4 + wv, nw = gridDim.x * 4;
  for (int p = wid; p < PTS; p += nw) {
    float v0, v1;
    if (mode == 0) {  // input = g_raw [2][PTS][64]
      v0 = in[(size_t)p * 64 + lane];
      v1 = in[(size_t)PTS * 64 + (size_t)p * 64 + lane];
    } else {          // input = h1 raw [PTS][128]
      v0 = in[(size_t)p * 128 + lane];
      v1 = in[(size_t)p * 128 + 64 + lane];
    }
    v0 = (v0 - m0) * s0; v0 = v0 > 0.f ? v0 : 0.f;
    v1 = (v1 - m1) * s1; v1 = v1 > 0.f ? v1 : 0.f;
    rowS[wv][lane] = v0;
    rowS[wv][64 + lane] = v1;
    if (aggout) {
      aggout[(size_t)p * 128 + lane] = v0;
      aggout[(size_t)p * 128 + 64 + lane] = v1;
    }
    __syncthreads();
#pragma unroll
    for (int h = 0; h < 2; ++h) {
      const int o = h * 64 + lane;
      float acc = 0.f;
#pragma unroll
      for (int c = 0; c < 128; ++c) acc += rowS[wv][c] * wlds[o * 129 + c];
      rowout[(size_t)p * 128 + o] = acc;
      if (h == 0) { a1s0 += acc; a2s0 += acc * acc; }
      else        { a1s1 += acc; a2s1 += acc * acc; }
    }
    __syncthreads();
  }
  atomicAdd(&dstat[dsOut + lane], (double)a1s0);
  atomicAdd(&dstat[dsOut + 64 + lane], (double)a1s1);
  atomicAdd(&dstat[dsOut + 128 + lane], (double)a2s0);
  atomicAdd(&dstat[dsOut + 128 + 64 + lane], (double)a2s1);
}

// ---------------- final: out = relu(bn(h2) + agg) ----------------
__global__ __launch_bounds__(256) void final_kernel(const float* __restrict__ h2,
                                                    const float* __restrict__ agg,
                                                    const float* __restrict__ bnp,
                                                    float* __restrict__ out) {
  const size_t e = (size_t)blockIdx.x * 256 + threadIdx.x;
  const int ch = (int)(e & 127);
  const float m = bnp[DS_H2 + ch], s = bnp[DS_H2 + 128 + ch];
  float v = (h2[e] - m) * s + agg[e];
  out[e] = v > 0.f ? v : 0.f;
}

extern "C" void kernel_launch(void* const* d_in, const int* in_sizes, int n_in,
                              void* d_out, int out_size, void* d_ws, size_t ws_size,
                              hipStream_t stream) {
  (void)in_sizes; (void)n_in; (void)out_size; (void)ws_size;
  const float* xyz      = (const float*)d_in[0];
  const float* features = (const float*)d_in[1];
  const float* w_lse1   = (const float*)d_in[2];
  const float* w_lse2   = (const float*)d_in[3];
  const float* ap1_sw1  = (const float*)d_in[4];
  const float* ap1_sw2  = (const float*)d_in[5];
  const float* ap1_sb2  = (const float*)d_in[6];
  const float* ap1_mw   = (const float*)d_in[7];
  const float* ap2_sw1  = (const float*)d_in[8];
  const float* ap2_sw2  = (const float*)d_in[9];
  const float* ap2_sb2  = (const float*)d_in[10];
  const float* ap2_mw   = (const float*)d_in[11];
  const float* drb_w1   = (const float*)d_in[12];
  const float* drb_w2   = (const float*)d_in[13];

  char* ws = (char*)d_ws;
  float*  knn_d = (float*)(ws + OFF_A);
  int*    knn_j = (int*)(ws + OFF_B);
  int*    idx   = (int*)(ws + OFF_IDX);
  double* dstat = (double*)(ws + OFF_DST);
  float*  bnp   = (float*)(ws + OFF_BNP);
  float*  graw  = (float*)(ws + OFF_A);   // reuse after knn done
  float*  agg   = (float*)(ws + OFF_B);   // reuse after knn done
  float*  h1    = (float*)(ws + OFF_H1);
  float*  h2    = (float*)(ws + OFF_H2);
  float*  out   = (float*)d_out;

  hipMemsetAsync(dstat, 0, 1280 * sizeof(double), stream);

  knn_chunk_kernel<<<dim3(Nq / 256, CH, Bq), 256, 0, stream>>>(xyz, knn_d, knn_j);
  knn_merge_kernel<<<dim3(PTS / 256), 256, 0, stream>>>(knn_d, knn_j, idx);

  pass1_kernel<<<dim3(512, 2), 256, 0, stream>>>(xyz, features, idx, w_lse1, w_lse2, dstat);
  bn_finalize_kernel<<<1, 128, 0, stream>>>(dstat, bnp, DS_Y, 1.0 / ROWS);

  passA_kernel<<<dim3(640, 2), 256, 0, stream>>>(xyz, features, idx, w_lse1, w_lse2,
                                                 ap1_sw1, ap2_sw1, bnp, dstat);
  bn_finalize_kernel<<<1, 128, 0, stream>>>(dstat, bnp, DS_Z, 1.0 / ROWS);

  passB_kernel<<<dim3(384, 2), 256, 0, stream>>>(xyz, features, idx, w_lse1, w_lse2,
                                                 ap1_sw1, ap2_sw1, ap1_sw2, ap2_sw2,
                                                 ap1_sb2, ap2_sb2, ap1_mw, ap2_mw,
                                                 bnp, dstat, graw);
  bn_finalize_kernel<<<1, 128, 0, stream>>>(dstat, bnp, DS_G, 1.0 / PTS);

  drb_mm_kernel<<<dim3(512), 256, 0, stream>>>(graw, drb_w1, bnp, dstat, agg, h1,
                                               DS_G, DS_H1, 0);
  bn_finalize_kernel<<<1, 128, 0, stream>>>(dstat, bnp, DS_H1, 1.0 / PTS);

  drb_mm_kernel<<<dim3(512), 256, 0, stream>>>(h1, drb_w2, bnp, dstat, nullptr, h2,
                                               DS_H1, DS_H2, 1);
  bn_finalize_kernel<<<1, 128, 0, stream>>>(dstat, bnp, DS_H2, 1.0 / PTS);

  final_kernel<<<dim3(PTS * 128 / 256), 256, 0, stream>>>(h2, agg, bnp, out);
}